// Round 1
// baseline (437.534 us; speedup 1.0000x reference)
//
#include <hip/hip_runtime.h>
#include <math.h>

#define N_ROWS 8192
#define D_DIM  768
#define P_DIM  1024
#define KNOTS  17
#define NCHUNK 128
#define ROWS_PER_CHUNK (N_ROWS / NCHUNK)   // 64

#define BM 128
#define BN 128
#define BK 16
#define TM 8
#define TN 8

// ---------------- K1: column inverse norms of a (768 x 1024) ----------------
__global__ __launch_bounds__(256) void colnorm_kernel(const float* __restrict__ a,
                                                      float* __restrict__ inv_norm) {
    int p = blockIdx.x * 256 + threadIdx.x;   // 1024 threads total, coalesced over p
    float s = 0.f;
    for (int d = 0; d < D_DIM; ++d) {
        float v = a[d * P_DIM + p];
        s = fmaf(v, v, s);
    }
    inv_norm[p] = rsqrtf(s);
}

// ---------------- K2: fp32 GEMM  proj_raw = z @ a  (8192x768 * 768x1024) ----
__global__ __launch_bounds__(256) void gemm_kernel(const float* __restrict__ A,   // z
                                                   const float* __restrict__ B,   // a
                                                   float* __restrict__ C) {       // proj_raw
    __shared__ float As[BK][BM];
    __shared__ float Bs[BK][BN];
    const int tid = threadIdx.x;
    const int tx = tid & 15;        // 0..15 → column groups
    const int ty = tid >> 4;        // 0..15 → row groups (8 rows each)
    const int row0 = blockIdx.y * BM;
    const int col0 = blockIdx.x * BN;

    float acc[TM][TN] = {};

    for (int k0 = 0; k0 < D_DIM; k0 += BK) {
        // A tile: 128 rows x 16 cols = 512 float4, 2 per thread; store transposed
        #pragma unroll
        for (int i = 0; i < 2; ++i) {
            int idx = tid + i * 256;
            int r   = idx >> 2;      // 0..127
            int c4  = idx & 3;       // 0..3
            const float4 v = *reinterpret_cast<const float4*>(
                &A[(size_t)(row0 + r) * D_DIM + k0 + c4 * 4]);
            As[c4 * 4 + 0][r] = v.x;
            As[c4 * 4 + 1][r] = v.y;
            As[c4 * 4 + 2][r] = v.z;
            As[c4 * 4 + 3][r] = v.w;
        }
        // B tile: 16 rows x 128 cols = 512 float4, 2 per thread; direct layout
        #pragma unroll
        for (int i = 0; i < 2; ++i) {
            int idx = tid + i * 256;
            int r   = idx >> 5;      // 0..15
            int c4  = idx & 31;      // 0..31
            *reinterpret_cast<float4*>(&Bs[r][c4 * 4]) =
                *reinterpret_cast<const float4*>(
                    &B[(size_t)(k0 + r) * P_DIM + col0 + c4 * 4]);
        }
        __syncthreads();

        #pragma unroll
        for (int kk = 0; kk < BK; ++kk) {
            float am[TM], bn[TN];
            #pragma unroll
            for (int i = 0; i < TM; ++i) am[i] = As[kk][ty * TM + i];
            // split-column mapping: cols tx*4..tx*4+3  and  64+tx*4..64+tx*4+3
            #pragma unroll
            for (int j = 0; j < 4; ++j) bn[j]     = Bs[kk][tx * 4 + j];
            #pragma unroll
            for (int j = 0; j < 4; ++j) bn[4 + j] = Bs[kk][64 + tx * 4 + j];
            #pragma unroll
            for (int i = 0; i < TM; ++i)
                #pragma unroll
                for (int j = 0; j < TN; ++j)
                    acc[i][j] = fmaf(am[i], bn[j], acc[i][j]);
        }
        __syncthreads();
    }

    // C write: two coalesced float4 stores per row
    #pragma unroll
    for (int i = 0; i < TM; ++i) {
        size_t rowoff = (size_t)(row0 + ty * TM + i) * P_DIM;
        float4 v0 = make_float4(acc[i][0], acc[i][1], acc[i][2], acc[i][3]);
        float4 v1 = make_float4(acc[i][4], acc[i][5], acc[i][6], acc[i][7]);
        *reinterpret_cast<float4*>(&C[rowoff + col0 + tx * 4])      = v0;
        *reinterpret_cast<float4*>(&C[rowoff + col0 + 64 + tx * 4]) = v1;
    }
}

// ------- K3: normalize + sincos + Chebyshev recurrence + partial sums -------
// grid (P_DIM/256, NCHUNK); thread owns column p over ROWS_PER_CHUNK rows
__global__ __launch_bounds__(256) void cf_kernel(const float* __restrict__ C,
                                                 const float* __restrict__ inv_norm,
                                                 float* __restrict__ part) {
    const int t = threadIdx.x;
    const int p = blockIdx.x * 256 + t;
    const int chunk = blockIdx.y;
    const int r0 = chunk * ROWS_PER_CHUNK;
    const float inp = inv_norm[p];
    const float dt = 3.0f / (KNOTS - 1);   // 0.1875 exact

    float cs[KNOTS], ss[KNOTS];
    #pragma unroll
    for (int k = 0; k < KNOTS; ++k) { cs[k] = 0.f; ss[k] = 0.f; }

    for (int r = 0; r < ROWS_PER_CHUNK; ++r) {
        float x  = C[(size_t)(r0 + r) * P_DIM + p] * inp;
        float th = x * dt;
        float s1 = __sinf(th);
        float c1 = __cosf(th);
        float c2 = 2.f * c1;
        float ck_2 = 1.f, sk_2 = 0.f;      // k = 0
        float ck_1 = c1, sk_1 = s1;        // k = 1
        cs[0] += 1.f;
        cs[1] += c1; ss[1] += s1;
        #pragma unroll
        for (int k = 2; k < KNOTS; ++k) {
            float ck = fmaf(c2, ck_1, -ck_2);
            float sk = fmaf(c2, sk_1, -sk_2);
            cs[k] += ck; ss[k] += sk;
            ck_2 = ck_1; sk_2 = sk_1;
            ck_1 = ck;  sk_1 = sk;
        }
    }
    // part[(chunk*34 + j)][p], coalesced over p
    #pragma unroll
    for (int k = 0; k < KNOTS; ++k) {
        part[((size_t)chunk * 2 * KNOTS + k) * P_DIM + p]         = cs[k];
        part[((size_t)chunk * 2 * KNOTS + KNOTS + k) * P_DIM + p] = ss[k];
    }
}

// ---------------- K4: reduce chunks, epilogue, scalar out -------------------
__global__ __launch_bounds__(1024) void finalize_kernel(const float* __restrict__ part,
                                                        float* __restrict__ out) {
    const int p = threadIdx.x;   // single block of 1024
    float cs[KNOTS] = {}, ss[KNOTS] = {};
    for (int c = 0; c < NCHUNK; ++c) {
        #pragma unroll
        for (int k = 0; k < KNOTS; ++k) {
            cs[k] += part[((size_t)c * 2 * KNOTS + k) * P_DIM + p];
            ss[k] += part[((size_t)c * 2 * KNOTS + KNOTS + k) * P_DIM + p];
        }
    }
    const float dt = 3.0f / (KNOTS - 1);
    const float inv_n = 1.0f / (float)N_ROWS;
    float contrib = 0.f;
    #pragma unroll
    for (int k = 0; k < KNOTS; ++k) {
        float tk   = dt * (float)k;
        float phik = expf(-0.5f * tk * tk);
        float wk   = (k == 0 || k == KNOTS - 1) ? dt : 2.f * dt;
        float cm   = cs[k] * inv_n - phik;
        float sm   = ss[k] * inv_n;
        contrib += wk * phik * (cm * cm + sm * sm);
    }
    __shared__ float red[1024];
    red[p] = contrib;
    __syncthreads();
    for (int sft = 512; sft > 0; sft >>= 1) {
        if (p < sft) red[p] += red[p + sft];
        __syncthreads();
    }
    if (p == 0) out[0] = red[0] * (float)N_ROWS / (float)P_DIM;
}

extern "C" void kernel_launch(void* const* d_in, const int* in_sizes, int n_in,
                              void* d_out, int out_size, void* d_ws, size_t ws_size,
                              hipStream_t stream) {
    const float* z = (const float*)d_in[0];   // 8192 x 768
    const float* a = (const float*)d_in[1];   // 768 x 1024
    float* out = (float*)d_out;

    char* ws = (char*)d_ws;
    float* inv_norm = (float*)ws;                                        // 4 KB
    float* proj     = (float*)(ws + 4096);                               // 32 MB
    float* part     = (float*)(ws + 4096 + (size_t)N_ROWS * P_DIM * 4);  // ~17.8 MB

    colnorm_kernel<<<dim3(P_DIM / 256), 256, 0, stream>>>(a, inv_norm);
    gemm_kernel<<<dim3(P_DIM / BN, N_ROWS / BM), 256, 0, stream>>>(z, a, proj);
    cf_kernel<<<dim3(P_DIM / 256, NCHUNK), 256, 0, stream>>>(proj, inv_norm, part);
    finalize_kernel<<<1, 1024, 0, stream>>>(part, out);
}

// Round 3
// 151.917 us; speedup vs baseline: 2.8801x; 2.8801x over previous
//
#include <hip/hip_runtime.h>
#include <math.h>

typedef __attribute__((ext_vector_type(8))) short bf16x8;
typedef __attribute__((ext_vector_type(4))) float f32x4;

#define N_ROWS 8192
#define D_DIM  768
#define P_DIM  1024
#define KNOTS  17
#define NCHUNK 64
#define RPC    128   // rows per chunk in cf pass

// ---- bf16 round-to-nearest-even (finite data only) ----
__device__ inline unsigned short f2bf(float f) {
    union { float f; unsigned int u; } x; x.f = f;
    unsigned int r = x.u + 0x7FFFu + ((x.u >> 16) & 1u);
    return (unsigned short)(r >> 16);
}

// ---- async global->LDS, 16B per lane ----
__device__ inline void gload_lds16(const unsigned short* g, const unsigned short* l) {
    auto gp = reinterpret_cast<const __attribute__((address_space(1))) char*>(
        reinterpret_cast<uintptr_t>(g));
    auto lp = reinterpret_cast<__attribute__((address_space(3))) char*>(
        (uintptr_t)(unsigned int)reinterpret_cast<uintptr_t>(l));
    __builtin_amdgcn_global_load_lds(gp, lp, 16, 0, 0);
}

// ---------------- K1: column sum-of-squares of a (atomic partials) ----------
__global__ __launch_bounds__(256) void colsq_kernel(const float* __restrict__ a,
                                                    float* __restrict__ colsq) {
    int p  = blockIdx.x * 256 + threadIdx.x;
    int d0 = blockIdx.y * 64;
    float s = 0.f;
    for (int d = 0; d < 64; ++d) {
        float v = a[(size_t)(d0 + d) * P_DIM + p];
        s = fmaf(v, v, s);
    }
    atomicAdd(&colsq[p], s);
}

// ---------------- K2: z (fp32) -> zh (bf16), elementwise -------------------
__global__ __launch_bounds__(256) void zconv_kernel(const float* __restrict__ z,
                                                    unsigned short* __restrict__ zh) {
    size_t i = ((size_t)blockIdx.x * 256 + threadIdx.x) * 4;
    float4 v = *reinterpret_cast<const float4*>(z + i);
    ushort4 o;
    o.x = f2bf(v.x); o.y = f2bf(v.y); o.z = f2bf(v.z); o.w = f2bf(v.w);
    *reinterpret_cast<ushort4*>(zh + i) = o;
}

// ------- K3: a (768x1024) -> Bt (1024x768 bf16), normalized columns --------
__global__ __launch_bounds__(256) void atconv_kernel(const float* __restrict__ a,
                                                     const float* __restrict__ colsq,
                                                     unsigned short* __restrict__ Bt) {
    __shared__ float tile[64][65];
    const int d0 = blockIdx.x * 64, p0 = blockIdx.y * 64;
    const int tid = threadIdx.x;
    #pragma unroll
    for (int pass = 0; pass < 16; ++pass) {
        int idx = pass * 256 + tid;
        int dr = idx >> 6, pc = idx & 63;
        tile[dr][pc] = a[(size_t)(d0 + dr) * P_DIM + p0 + pc];
    }
    __syncthreads();
    #pragma unroll
    for (int pass = 0; pass < 16; ++pass) {
        int idx = pass * 256 + tid;
        int pr = idx >> 6, dc = idx & 63;
        float inv = rsqrtf(colsq[p0 + pr]);
        Bt[(size_t)(p0 + pr) * D_DIM + d0 + dc] = f2bf(tile[dc][pr] * inv);
    }
}

// ---------------- K4: bf16 MFMA GEMM  proj = zh @ Bt^T  --------------------
// M=8192 N=1024 K=768; A row-major (M x K), B row-major (N x K) == B^T input.
// 128x128 tile, BK=64, 4 waves (2x2), each wave 64x64 via 4x4 16x16x32 frags.
__global__ __launch_bounds__(256, 2) void gemm_kernel(const unsigned short* __restrict__ A,
                                                      const unsigned short* __restrict__ B,
                                                      float* __restrict__ C) {
    __shared__ unsigned short As[128 * 64];
    __shared__ unsigned short Bs[128 * 64];
    const int tid  = threadIdx.x;
    const int lane = tid & 63;
    const int wave = tid >> 6;
    const int wr = wave >> 1, wc = wave & 1;
    const int row0 = blockIdx.y * 128;
    const int col0 = blockIdx.x * 128;

    // staging: wave stages rows [wave*32, wave*32+32) of each tile, 4 insts x 8 rows
    const int srow  = wave * 32 + (lane >> 3);
    const int skoff = (lane & 7) * 8;
    const unsigned short* Ag = A + (size_t)(row0 + srow) * D_DIM + skoff;
    const unsigned short* Bg = B + (size_t)(col0 + srow) * D_DIM + skoff;
    const unsigned short* Asw = As + (wave * 32) * 64;
    const unsigned short* Bsw = Bs + (wave * 32) * 64;

    f32x4 acc[4][4] = {};

    for (int k0 = 0; k0 < D_DIM; k0 += 64) {
        #pragma unroll
        for (int i = 0; i < 4; ++i) {
            gload_lds16(Ag + k0 + i * (8 * D_DIM), Asw + i * (8 * 64));
            gload_lds16(Bg + k0 + i * (8 * D_DIM), Bsw + i * (8 * 64));
        }
        __syncthreads();
        #pragma unroll
        for (int kk = 0; kk < 2; ++kk) {
            bf16x8 af[4], bfr[4];
            const int kg = kk * 4 + (lane >> 4);   // k-group of 8 within BK=64
            #pragma unroll
            for (int mi = 0; mi < 4; ++mi)
                af[mi] = *reinterpret_cast<const bf16x8*>(
                    &As[(wr * 64 + mi * 16 + (lane & 15)) * 64 + kg * 8]);
            #pragma unroll
            for (int ni = 0; ni < 4; ++ni)
                bfr[ni] = *reinterpret_cast<const bf16x8*>(
                    &Bs[(wc * 64 + ni * 16 + (lane & 15)) * 64 + kg * 8]);
            #pragma unroll
            for (int mi = 0; mi < 4; ++mi)
                #pragma unroll
                for (int ni = 0; ni < 4; ++ni)
                    acc[mi][ni] = __builtin_amdgcn_mfma_f32_16x16x32_bf16(
                        af[mi], bfr[ni], acc[mi][ni], 0, 0, 0);
        }
        __syncthreads();
    }

    // C layout per frag: col = lane&15, row = (lane>>4)*4 + j   [measured m89/m91]
    #pragma unroll
    for (int mi = 0; mi < 4; ++mi)
        #pragma unroll
        for (int ni = 0; ni < 4; ++ni) {
            int col = col0 + wc * 64 + ni * 16 + (lane & 15);
            int row = row0 + wr * 64 + mi * 16 + ((lane >> 4) << 2);
            #pragma unroll
            for (int j = 0; j < 4; ++j)
                C[(size_t)(row + j) * P_DIM + col] = acc[mi][ni][j];
        }
}

// ------- K5: sincos + Chebyshev recurrence + per-chunk partial sums --------
__global__ __launch_bounds__(256) void cf_kernel(const float* __restrict__ C,
                                                 float* __restrict__ part) {
    const int t = threadIdx.x;
    const int p = blockIdx.x * 256 + t;
    const int chunk = blockIdx.y;
    const int r0 = chunk * RPC;
    const float dt = 0.1875f;   // 3/16 exact

    float cs[KNOTS], ss[KNOTS];
    #pragma unroll
    for (int k = 0; k < KNOTS; ++k) { cs[k] = 0.f; ss[k] = 0.f; }

    for (int r = 0; r < RPC; ++r) {
        float x  = C[(size_t)(r0 + r) * P_DIM + p];
        float th = x * dt;
        float s1 = __sinf(th);
        float c1 = __cosf(th);
        float c2 = 2.f * c1;
        float ck_2 = 1.f, sk_2 = 0.f;
        float ck_1 = c1, sk_1 = s1;
        cs[0] += 1.f;
        cs[1] += c1; ss[1] += s1;
        #pragma unroll
        for (int k = 2; k < KNOTS; ++k) {
            float ck = fmaf(c2, ck_1, -ck_2);
            float sk = fmaf(c2, sk_1, -sk_2);
            cs[k] += ck; ss[k] += sk;
            ck_2 = ck_1; sk_2 = sk_1;
            ck_1 = ck;  sk_1 = sk;
        }
    }
    #pragma unroll
    for (int k = 0; k < KNOTS; ++k) {
        part[((size_t)chunk * 2 * KNOTS + k) * P_DIM + p]         = cs[k];
        part[((size_t)chunk * 2 * KNOTS + KNOTS + k) * P_DIM + p] = ss[k];
    }
}

// ---------------- K6: parallel chunk reduction (34*1024 outputs) -----------
__global__ __launch_bounds__(256) void red1_kernel(const float* __restrict__ part,
                                                   float* __restrict__ sums) {
    int g = blockIdx.x * 256 + threadIdx.x;   // [0, 34*1024)
    float s = 0.f;
    for (int c = 0; c < NCHUNK; ++c)
        s += part[(size_t)c * 2 * KNOTS * P_DIM + g];
    sums[g] = s;
}

// ---------------- K7: epilogue + scalar out --------------------------------
__global__ __launch_bounds__(1024) void red2_kernel(const float* __restrict__ sums,
                                                    float* __restrict__ out) {
    const int p = threadIdx.x;
    const float dt = 0.1875f;
    const float inv_n = 1.0f / (float)N_ROWS;
    float contrib = 0.f;
    #pragma unroll
    for (int k = 0; k < KNOTS; ++k) {
        float cm   = sums[k * P_DIM + p] * inv_n;
        float sm   = sums[(KNOTS + k) * P_DIM + p] * inv_n;
        float tk   = dt * (float)k;
        float phik = expf(-0.5f * tk * tk);
        float wk   = (k == 0 || k == KNOTS - 1) ? dt : 2.f * dt;
        float d    = cm - phik;
        contrib += wk * phik * (d * d + sm * sm);
    }
    __shared__ float red[1024];
    red[p] = contrib;
    __syncthreads();
    for (int sft = 512; sft > 0; sft >>= 1) {
        if (p < sft) red[p] += red[p + sft];
        __syncthreads();
    }
    if (p == 0) out[0] = red[0] * (float)N_ROWS / (float)P_DIM;
}

extern "C" void kernel_launch(void* const* d_in, const int* in_sizes, int n_in,
                              void* d_out, int out_size, void* d_ws, size_t ws_size,
                              hipStream_t stream) {
    const float* z = (const float*)d_in[0];   // 8192 x 768
    const float* a = (const float*)d_in[1];   // 768 x 1024
    float* out = (float*)d_out;

    char* ws = (char*)d_ws;
    float*          colsq = (float*)ws;                               // 4 KB
    unsigned short* zh    = (unsigned short*)(ws + 4096);             // 12,582,912 B
    unsigned short* Bt    = (unsigned short*)(ws + 4096 + 12582912);  // 1,572,864 B
    float*          proj  = (float*)(ws + 4096 + 12582912 + 1572864); // 33,554,432 B
    // aliases (regions dead after GEMM):
    float* part = (float*)zh;    // 64*34*1024*4 = 8.9 MB  <= zh size
    float* sums = (float*)Bt;    // 34*1024*4 = 136 KB     <= Bt size

    hipMemsetAsync(colsq, 0, P_DIM * sizeof(float), stream);
    colsq_kernel<<<dim3(P_DIM / 256, D_DIM / 64), 256, 0, stream>>>(a, colsq);
    zconv_kernel<<<dim3(N_ROWS * D_DIM / (256 * 4)), 256, 0, stream>>>(z, zh);
    atconv_kernel<<<dim3(D_DIM / 64, P_DIM / 64), 256, 0, stream>>>(a, colsq, Bt);
    gemm_kernel<<<dim3(P_DIM / 128, N_ROWS / 128), 256, 0, stream>>>(zh, Bt, proj);
    cf_kernel<<<dim3(P_DIM / 256, NCHUNK), 256, 0, stream>>>(proj, part);
    red1_kernel<<<dim3(2 * KNOTS * P_DIM / 256), 256, 0, stream>>>(part, sums);
    red2_kernel<<<1, 1024, 0, stream>>>(sums, out);
}

// Round 4
// 141.889 us; speedup vs baseline: 3.0836x; 1.0707x over previous
//
#include <hip/hip_runtime.h>
#include <math.h>

typedef __attribute__((ext_vector_type(8))) short bf16x8;
typedef __attribute__((ext_vector_type(4))) float f32x4;

#define N_ROWS 8192
#define D_DIM  768
#define P_DIM  1024
#define KNOTS  17
#define NRB    (N_ROWS / 128)   // 64 row-blocks = partial-sum chunks

// ---- bf16 round-to-nearest-even (finite data only) ----
__device__ inline unsigned short f2bf(float f) {
    union { float f; unsigned int u; } x; x.f = f;
    unsigned int r = x.u + 0x7FFFu + ((x.u >> 16) & 1u);
    return (unsigned short)(r >> 16);
}

// ---- async global->LDS, 16B per lane ----
__device__ inline void gload_lds16(const unsigned short* g, const unsigned short* l) {
    auto gp = reinterpret_cast<const __attribute__((address_space(1))) char*>(
        reinterpret_cast<uintptr_t>(g));
    auto lp = reinterpret_cast<__attribute__((address_space(3))) char*>(
        (uintptr_t)(unsigned int)reinterpret_cast<uintptr_t>(l));
    __builtin_amdgcn_global_load_lds(gp, lp, 16, 0, 0);
}

// ---------------- K1: column sum-of-squares of a (atomic partials) ----------
__global__ __launch_bounds__(256) void colsq_kernel(const float* __restrict__ a,
                                                    float* __restrict__ colsq) {
    int p  = blockIdx.x * 256 + threadIdx.x;
    int d0 = blockIdx.y * 64;
    float s = 0.f;
    for (int d = 0; d < 64; ++d) {
        float v = a[(size_t)(d0 + d) * P_DIM + p];
        s = fmaf(v, v, s);
    }
    atomicAdd(&colsq[p], s);
}

// ---------------- K2: z (fp32) -> zh (bf16), elementwise -------------------
__global__ __launch_bounds__(256) void zconv_kernel(const float* __restrict__ z,
                                                    unsigned short* __restrict__ zh) {
    size_t i = ((size_t)blockIdx.x * 256 + threadIdx.x) * 4;
    float4 v = *reinterpret_cast<const float4*>(z + i);
    ushort4 o;
    o.x = f2bf(v.x); o.y = f2bf(v.y); o.z = f2bf(v.z); o.w = f2bf(v.w);
    *reinterpret_cast<ushort4*>(zh + i) = o;
}

// ------- K3: a (768x1024) -> Bt (1024x768 bf16), normalized columns --------
__global__ __launch_bounds__(256) void atconv_kernel(const float* __restrict__ a,
                                                     const float* __restrict__ colsq,
                                                     unsigned short* __restrict__ Bt) {
    __shared__ float tile[64][65];
    const int d0 = blockIdx.x * 64, p0 = blockIdx.y * 64;
    const int tid = threadIdx.x;
    #pragma unroll
    for (int pass = 0; pass < 16; ++pass) {
        int idx = pass * 256 + tid;
        int dr = idx >> 6, pc = idx & 63;
        tile[dr][pc] = a[(size_t)(d0 + dr) * P_DIM + p0 + pc];
    }
    __syncthreads();
    #pragma unroll
    for (int pass = 0; pass < 16; ++pass) {
        int idx = pass * 256 + tid;
        int pr = idx >> 6, dc = idx & 63;
        float inv = rsqrtf(colsq[p0 + pr]);
        Bt[(size_t)(p0 + pr) * D_DIM + d0 + dc] = f2bf(tile[dc][pr] * inv);
    }
}

// ------- K4: fused bf16 MFMA GEMM + sincos/Chebyshev partial sums ----------
// proj tile (128x128) stays in registers; per-block partial (34 x 128) out.
__global__ __launch_bounds__(256) void gemmcf_kernel(const unsigned short* __restrict__ A,
                                                     const unsigned short* __restrict__ B,
                                                     float* __restrict__ part) {
    __shared__ unsigned short As[128 * 64];
    __shared__ unsigned short Bs[128 * 64];
    __shared__ float lds_red[2 * KNOTS][128];   // 17.4 KB
    const int tid  = threadIdx.x;
    const int lane = tid & 63;
    const int wave = tid >> 6;
    const int wr = wave >> 1, wc = wave & 1;
    const int row0 = blockIdx.y * 128;
    const int col0 = blockIdx.x * 128;

    // staging: wave stages rows [wave*32, wave*32+32) of each tile
    const int srow  = wave * 32 + (lane >> 3);
    const int skoff = (lane & 7) * 8;
    const unsigned short* Ag = A + (size_t)(row0 + srow) * D_DIM + skoff;
    const unsigned short* Bg = B + (size_t)(col0 + srow) * D_DIM + skoff;
    const unsigned short* Asw = As + (wave * 32) * 64;
    const unsigned short* Bsw = Bs + (wave * 32) * 64;

    // zero the reduction buffer while waiting on nothing
    #pragma unroll
    for (int i = 0; i < 2 * KNOTS * 128 / 256; ++i)
        ((float*)lds_red)[i * 256 + tid] = 0.f;

    f32x4 acc[4][4] = {};

    for (int k0 = 0; k0 < D_DIM; k0 += 64) {
        #pragma unroll
        for (int i = 0; i < 4; ++i) {
            gload_lds16(Ag + k0 + i * (8 * D_DIM), Asw + i * (8 * 64));
            gload_lds16(Bg + k0 + i * (8 * D_DIM), Bsw + i * (8 * 64));
        }
        __syncthreads();
        #pragma unroll
        for (int kk = 0; kk < 2; ++kk) {
            bf16x8 af[4], bfr[4];
            const int kg = kk * 4 + (lane >> 4);
            #pragma unroll
            for (int mi = 0; mi < 4; ++mi)
                af[mi] = *reinterpret_cast<const bf16x8*>(
                    &As[(wr * 64 + mi * 16 + (lane & 15)) * 64 + kg * 8]);
            #pragma unroll
            for (int ni = 0; ni < 4; ++ni)
                bfr[ni] = *reinterpret_cast<const bf16x8*>(
                    &Bs[(wc * 64 + ni * 16 + (lane & 15)) * 64 + kg * 8]);
            #pragma unroll
            for (int mi = 0; mi < 4; ++mi)
                #pragma unroll
                for (int ni = 0; ni < 4; ++ni)
                    acc[mi][ni] = __builtin_amdgcn_mfma_f32_16x16x32_bf16(
                        af[mi], bfr[ni], acc[mi][ni], 0, 0, 0);
        }
        __syncthreads();
    }

    // ---- fused epilogue: per-column cos/sin sums over this block's 128 rows.
    // Frag layout: col = wc*64 + ni*16 + (lane&15); for fixed (lane, ni) all
    // 16 values (mi, j) are rows of that ONE column -> no transpose needed.
    const float dt = 0.1875f;   // 3/16 exact
    #pragma unroll
    for (int ni = 0; ni < 4; ++ni) {
        float csl[KNOTS], ssl[KNOTS];
        #pragma unroll
        for (int k = 0; k < KNOTS; ++k) { csl[k] = 0.f; ssl[k] = 0.f; }
        #pragma unroll
        for (int mi = 0; mi < 4; ++mi)
            #pragma unroll
            for (int j = 0; j < 4; ++j) {
                float th = acc[mi][ni][j] * dt;
                float s1 = __sinf(th);
                float c1 = __cosf(th);
                float c2 = 2.f * c1;
                float ckm2 = 1.f, skm2 = 0.f;
                float ckm1 = c1,  skm1 = s1;
                csl[0] += 1.f;
                csl[1] += c1; ssl[1] += s1;
                #pragma unroll
                for (int k = 2; k < KNOTS; ++k) {
                    float ck = fmaf(c2, ckm1, -ckm2);
                    float sk = fmaf(c2, skm1, -skm2);
                    csl[k] += ck; ssl[k] += sk;
                    ckm2 = ckm1; skm2 = skm1;
                    ckm1 = ck;   skm1 = sk;
                }
            }
        // reduce across the 4 row-lane-groups holding the same column
        #pragma unroll
        for (int k = 0; k < KNOTS; ++k) {
            csl[k] += __shfl_xor(csl[k], 16);
            csl[k] += __shfl_xor(csl[k], 32);
            ssl[k] += __shfl_xor(ssl[k], 16);
            ssl[k] += __shfl_xor(ssl[k], 32);
        }
        if (lane < 16) {
            int col = wc * 64 + ni * 16 + lane;
            #pragma unroll
            for (int k = 0; k < KNOTS; ++k) {
                atomicAdd(&lds_red[k][col], csl[k]);           // cols hit distinct banks
                atomicAdd(&lds_red[KNOTS + k][col], ssl[k]);   // 2-way (wr) contention max
            }
        }
    }
    __syncthreads();

    // part[by][j][1024] — each block owns its (by, col-range) slice, no atomics
    #pragma unroll
    for (int i = 0; i < 2 * KNOTS * 128 / 256; ++i) {
        int idx = i * 256 + tid;
        int j = idx >> 7, c = idx & 127;
        part[((size_t)blockIdx.y * 2 * KNOTS + j) * P_DIM + col0 + c] =
            ((float*)lds_red)[idx];
    }
}

// ---------------- K5: parallel chunk reduction (34*1024 outputs) -----------
__global__ __launch_bounds__(256) void red1_kernel(const float* __restrict__ part,
                                                   float* __restrict__ sums) {
    int g = blockIdx.x * 256 + threadIdx.x;   // [0, 34*1024)
    float s = 0.f;
    for (int c = 0; c < NRB; ++c)
        s += part[(size_t)c * 2 * KNOTS * P_DIM + g];
    sums[g] = s;
}

// ---------------- K6: epilogue + scalar out --------------------------------
__global__ __launch_bounds__(1024) void red2_kernel(const float* __restrict__ sums,
                                                    float* __restrict__ out) {
    const int p = threadIdx.x;
    const float dt = 0.1875f;
    const float inv_n = 1.0f / (float)N_ROWS;
    float contrib = 0.f;
    #pragma unroll
    for (int k = 0; k < KNOTS; ++k) {
        float cm   = sums[k * P_DIM + p] * inv_n;
        float sm   = sums[(KNOTS + k) * P_DIM + p] * inv_n;
        float tk   = dt * (float)k;
        float phik = expf(-0.5f * tk * tk);
        float wk   = (k == 0 || k == KNOTS - 1) ? dt : 2.f * dt;
        float d    = cm - phik;
        contrib += wk * phik * (d * d + sm * sm);
    }
    __shared__ float red[1024];
    red[p] = contrib;
    __syncthreads();
    for (int sft = 512; sft > 0; sft >>= 1) {
        if (p < sft) red[p] += red[p + sft];
        __syncthreads();
    }
    if (p == 0) out[0] = red[0] * (float)N_ROWS / (float)P_DIM;
}

extern "C" void kernel_launch(void* const* d_in, const int* in_sizes, int n_in,
                              void* d_out, int out_size, void* d_ws, size_t ws_size,
                              hipStream_t stream) {
    const float* z = (const float*)d_in[0];   // 8192 x 768
    const float* a = (const float*)d_in[1];   // 768 x 1024
    float* out = (float*)d_out;

    char* ws = (char*)d_ws;                                      // all disjoint, ~23.2 MB
    float*          colsq = (float*)ws;                          // 4 KB
    unsigned short* zh    = (unsigned short*)(ws + 4096);        // 12.6 MB
    unsigned short* Bt    = (unsigned short*)(ws + 4096 + 12582912);            // 1.5 MB
    float*          part  = (float*)(ws + 4096 + 12582912 + 1572864);           // 8.9 MB
    float*          sums  = (float*)(ws + 4096 + 12582912 + 1572864 + 8912896); // 136 KB

    hipMemsetAsync(colsq, 0, P_DIM * sizeof(float), stream);
    colsq_kernel<<<dim3(P_DIM / 256, D_DIM / 64), 256, 0, stream>>>(a, colsq);
    zconv_kernel<<<dim3(N_ROWS * D_DIM / (256 * 4)), 256, 0, stream>>>(z, zh);
    atconv_kernel<<<dim3(D_DIM / 64, P_DIM / 64), 256, 0, stream>>>(a, colsq, Bt);
    gemmcf_kernel<<<dim3(P_DIM / 128, N_ROWS / 128), 256, 0, stream>>>(zh, Bt, part);
    red1_kernel<<<dim3(2 * KNOTS * P_DIM / 256), 256, 0, stream>>>(part, sums);
    red2_kernel<<<1, 1024, 0, stream>>>(sums, out);
}

// Round 6
// 129.033 us; speedup vs baseline: 3.3909x; 1.0996x over previous
//
#include <hip/hip_runtime.h>
#include <math.h>

typedef __attribute__((ext_vector_type(8))) short bf16x8;
typedef __attribute__((ext_vector_type(4))) float f32x4;

#define N_ROWS 8192
#define D_DIM  768
#define P_DIM  1024
#define KNOTS  17
#define NK     16                 // knots 1..16 (k=0 term is exactly zero)
#define NCH    128                // partial chunks: 64 row-blocks x 2 wr-halves

// ---- bf16 round-to-nearest-even (finite data only) ----
__device__ inline unsigned short f2bf(float f) {
    union { float f; unsigned int u; } x; x.f = f;
    unsigned int r = x.u + 0x7FFFu + ((x.u >> 16) & 1u);
    return (unsigned short)(r >> 16);
}

// ---- async global->LDS, 16B per lane ----
__device__ inline void gload_lds16(const unsigned short* g, const unsigned short* l) {
    auto gp = reinterpret_cast<const __attribute__((address_space(1))) char*>(
        reinterpret_cast<uintptr_t>(g));
    auto lp = reinterpret_cast<__attribute__((address_space(3))) char*>(
        (uintptr_t)(unsigned int)reinterpret_cast<uintptr_t>(l));
    __builtin_amdgcn_global_load_lds(gp, lp, 16, 0, 0);
}

// ---------------- K1: column sum-of-squares of a (atomic partials) ----------
__global__ __launch_bounds__(256) void colsq_kernel(const float* __restrict__ a,
                                                    float* __restrict__ colsq) {
    int p  = blockIdx.x * 256 + threadIdx.x;
    int d0 = blockIdx.y * 64;
    float s = 0.f;
    for (int d = 0; d < 64; ++d) {
        float v = a[(size_t)(d0 + d) * P_DIM + p];
        s = fmaf(v, v, s);
    }
    atomicAdd(&colsq[p], s);
}

// ---------------- K2: z (fp32) -> zh (bf16), elementwise -------------------
__global__ __launch_bounds__(256) void zconv_kernel(const float* __restrict__ z,
                                                    unsigned short* __restrict__ zh) {
    size_t i = ((size_t)blockIdx.x * 256 + threadIdx.x) * 4;
    float4 v = *reinterpret_cast<const float4*>(z + i);
    ushort4 o;
    o.x = f2bf(v.x); o.y = f2bf(v.y); o.z = f2bf(v.z); o.w = f2bf(v.w);
    *reinterpret_cast<ushort4*>(zh + i) = o;
}

// ------- K3: a (768x1024) -> Bt (1024x768 bf16), normalized columns --------
__global__ __launch_bounds__(256) void atconv_kernel(const float* __restrict__ a,
                                                     const float* __restrict__ colsq,
                                                     unsigned short* __restrict__ Bt) {
    __shared__ float tile[64][65];
    const int d0 = blockIdx.x * 64, p0 = blockIdx.y * 64;
    const int tid = threadIdx.x;
    #pragma unroll
    for (int pass = 0; pass < 16; ++pass) {
        int idx = pass * 256 + tid;
        int dr = idx >> 6, pc = idx & 63;
        tile[dr][pc] = a[(size_t)(d0 + dr) * P_DIM + p0 + pc];
    }
    __syncthreads();
    #pragma unroll
    for (int pass = 0; pass < 16; ++pass) {
        int idx = pass * 256 + tid;
        int pr = idx >> 6, dc = idx & 63;
        float inv = rsqrtf(colsq[p0 + pr]);
        Bt[(size_t)(p0 + pr) * D_DIM + d0 + dc] = f2bf(tile[dc][pr] * inv);
    }
}

// ------- K4: fused bf16 MFMA GEMM + sincos/Chebyshev partial sums ----------
// 128x128 tile, 512 threads = 8 waves (2 wr x 4 wc), wave tile 64x32,
// acc[4][2] of 16x16x32 frags. Per-(block, wr) partials, no LDS reduction.
__global__ __launch_bounds__(512, 4) void gemmcf_kernel(const unsigned short* __restrict__ A,
                                                        const unsigned short* __restrict__ B,
                                                        float* __restrict__ part) {
    __shared__ unsigned short As[128 * 64];
    __shared__ unsigned short Bs[128 * 64];
    const int tid  = threadIdx.x;
    const int lane = tid & 63;
    const int wave = tid >> 6;            // 0..7
    const int wr = wave >> 2, wc = wave & 3;

    // T1: XCD-aware swizzle (512 blocks, 8 XCDs, 64 blocks/XCD = 8 row-panels)
    const int bid = blockIdx.x + blockIdx.y * 8;
    const int swz = (bid & 7) * 64 + (bid >> 3);
    const int bx = swz & 7, by = swz >> 3;
    const int row0 = by * 128;
    const int col0 = bx * 128;

    // staging: wave stages rows [wave*16, wave*16+16) of each tile, 2 insts x 8 rows
    const int srow  = wave * 16 + (lane >> 3);
    const int skoff = (lane & 7) * 8;
    const unsigned short* Ag = A + (size_t)(row0 + srow) * D_DIM + skoff;
    const unsigned short* Bg = B + (size_t)(col0 + srow) * D_DIM + skoff;
    const unsigned short* Asw = As + (wave * 16) * 64;
    const unsigned short* Bsw = Bs + (wave * 16) * 64;

    f32x4 acc[4][2] = {};

    for (int k0 = 0; k0 < D_DIM; k0 += 64) {
        #pragma unroll
        for (int i = 0; i < 2; ++i) {
            gload_lds16(Ag + k0 + i * (8 * D_DIM), Asw + i * (8 * 64));
            gload_lds16(Bg + k0 + i * (8 * D_DIM), Bsw + i * (8 * 64));
        }
        __syncthreads();
        #pragma unroll
        for (int kk = 0; kk < 2; ++kk) {
            bf16x8 af[4], bfr[2];
            const int kg = kk * 4 + (lane >> 4);
            #pragma unroll
            for (int mi = 0; mi < 4; ++mi)
                af[mi] = *reinterpret_cast<const bf16x8*>(
                    &As[(wr * 64 + mi * 16 + (lane & 15)) * 64 + kg * 8]);
            #pragma unroll
            for (int ni = 0; ni < 2; ++ni)
                bfr[ni] = *reinterpret_cast<const bf16x8*>(
                    &Bs[(wc * 32 + ni * 16 + (lane & 15)) * 64 + kg * 8]);
            #pragma unroll
            for (int mi = 0; mi < 4; ++mi)
                #pragma unroll
                for (int ni = 0; ni < 2; ++ni)
                    acc[mi][ni] = __builtin_amdgcn_mfma_f32_16x16x32_bf16(
                        af[mi], bfr[ni], acc[mi][ni], 0, 0, 0);
        }
        __syncthreads();
    }

    // ---- fused epilogue: per-column cos/sin sums over this wave's 64 rows.
    // col = wc*32 + ni*16 + (lane&15): fixed per (lane&15, ni); the 16 values
    // (mi, j) are rows of that one column; butterfly 16/32 merges quarters.
    const float dt = 0.1875f;   // 3/16 exact
    #pragma unroll
    for (int ni = 0; ni < 2; ++ni) {
        float cs[NK], ss[NK];
        #pragma unroll
        for (int k = 0; k < NK; ++k) { cs[k] = 0.f; ss[k] = 0.f; }
        #pragma unroll
        for (int mi = 0; mi < 4; ++mi)
            #pragma unroll
            for (int j = 0; j < 4; ++j) {
                float th = acc[mi][ni][j] * dt;
                float s1 = __sinf(th);
                float c1 = __cosf(th);
                float c2 = 2.f * c1;
                float ckm2 = 1.f, skm2 = 0.f;
                float ckm1 = c1,  skm1 = s1;
                cs[0] += c1; ss[0] += s1;            // k = 1
                #pragma unroll
                for (int k = 2; k <= NK; ++k) {
                    float ck = fmaf(c2, ckm1, -ckm2);
                    float sk = fmaf(c2, skm1, -skm2);
                    cs[k - 1] += ck; ss[k - 1] += sk;
                    ckm2 = ckm1; skm2 = skm1;
                    ckm1 = ck;   skm1 = sk;
                }
            }
        #pragma unroll
        for (int k = 0; k < NK; ++k) {
            cs[k] += __shfl_xor(cs[k], 16);
            cs[k] += __shfl_xor(cs[k], 32);
            ss[k] += __shfl_xor(ss[k], 16);
            ss[k] += __shfl_xor(ss[k], 32);
        }
        if (lane < 16) {
            int col = col0 + wc * 32 + ni * 16 + lane;
            size_t base = ((size_t)(by * 2 + wr) * 2 * NK) * P_DIM + col;
            #pragma unroll
            for (int k = 0; k < NK; ++k) {
                part[base + (size_t)k * P_DIM]        = cs[k];
                part[base + (size_t)(NK + k) * P_DIM] = ss[k];
            }
        }
    }
}

// ---------------- K5: parallel chunk reduction (32*1024 outputs) -----------
__global__ __launch_bounds__(256) void red1_kernel(const float* __restrict__ part,
                                                   float* __restrict__ sums) {
    int g = blockIdx.x * 256 + threadIdx.x;   // [0, 2*NK*1024)
    float s = 0.f;
    for (int c = 0; c < NCH; ++c)
        s += part[(size_t)c * 2 * NK * P_DIM + g];
    sums[g] = s;
}

// ---------------- K6: epilogue + scalar out --------------------------------
__global__ __launch_bounds__(1024) void red2_kernel(const float* __restrict__ sums,
                                                    float* __restrict__ out) {
    const int p = threadIdx.x;
    const float dt = 0.1875f;
    const float inv_n = 1.0f / (float)N_ROWS;
    float contrib = 0.f;
    #pragma unroll
    for (int k = 1; k <= NK; ++k) {
        float cm   = sums[(k - 1) * P_DIM + p] * inv_n;
        float sm   = sums[(NK + k - 1) * P_DIM + p] * inv_n;
        float tk   = dt * (float)k;
        float phik = expf(-0.5f * tk * tk);
        float wk   = (k == KNOTS - 1) ? dt : 2.f * dt;
        float d    = cm - phik;
        contrib += wk * phik * (d * d + sm * sm);
    }
    __shared__ float red[1024];
    red[p] = contrib;
    __syncthreads();
    for (int sft = 512; sft > 0; sft >>= 1) {
        if (p < sft) red[p] += red[p + sft];
        __syncthreads();
    }
    if (p == 0) out[0] = red[0] * (float)N_ROWS / (float)P_DIM;
}

extern "C" void kernel_launch(void* const* d_in, const int* in_sizes, int n_in,
                              void* d_out, int out_size, void* d_ws, size_t ws_size,
                              hipStream_t stream) {
    const float* z = (const float*)d_in[0];   // 8192 x 768
    const float* a = (const float*)d_in[1];   // 768 x 1024
    float* out = (float*)d_out;

    char* ws = (char*)d_ws;                                      // all disjoint, ~31 MB
    float*          colsq = (float*)ws;                          // 4 KB
    unsigned short* zh    = (unsigned short*)(ws + 4096);        // 12.6 MB
    unsigned short* Bt    = (unsigned short*)(ws + 4096 + 12582912);            // 1.5 MB
    float*          part  = (float*)(ws + 4096 + 12582912 + 1572864);           // 16.8 MB
    float*          sums  = (float*)(ws + 4096 + 12582912 + 1572864 + 16777216);// 128 KB

    hipMemsetAsync(colsq, 0, P_DIM * sizeof(float), stream);
    colsq_kernel<<<dim3(P_DIM / 256, D_DIM / 64), 256, 0, stream>>>(a, colsq);
    zconv_kernel<<<dim3(N_ROWS * D_DIM / (256 * 4)), 256, 0, stream>>>(z, zh);
    atconv_kernel<<<dim3(D_DIM / 64, P_DIM / 64), 256, 0, stream>>>(a, colsq, Bt);
    gemmcf_kernel<<<dim3(P_DIM / 128, N_ROWS / 128), 512, 0, stream>>>(zh, Bt, part);
    red1_kernel<<<dim3(2 * NK * P_DIM / 256), 256, 0, stream>>>(part, sums);
    red2_kernel<<<1, 1024, 0, stream>>>(sums, out);
}

// Round 7
// 120.840 us; speedup vs baseline: 3.6208x; 1.0678x over previous
//
#include <hip/hip_runtime.h>
#include <math.h>

typedef __attribute__((ext_vector_type(8))) short bf16x8;
typedef __attribute__((ext_vector_type(4))) float f32x4;

#define N_ROWS 8192
#define D_DIM  768
#define P_DIM  1024
#define KNOTS  17
#define NK     16                 // knots 1..16 (k=0 term is exactly zero)
#define NCH    128                // partial chunks: 64 row-blocks x 2 wr-halves
#define KSTEPS 12                 // 768 / 64

// ---- bf16 round-to-nearest-even (finite data only) ----
__device__ inline unsigned short f2bf(float f) {
    union { float f; unsigned int u; } x; x.f = f;
    unsigned int r = x.u + 0x7FFFu + ((x.u >> 16) & 1u);
    return (unsigned short)(r >> 16);
}

// ---- async global->LDS, 16B per lane (LDS base wave-uniform, HW adds lane*16)
__device__ inline void gload_lds16(const unsigned short* g, const unsigned short* l) {
    auto gp = reinterpret_cast<const __attribute__((address_space(1))) char*>(
        reinterpret_cast<uintptr_t>(g));
    auto lp = reinterpret_cast<__attribute__((address_space(3))) char*>(
        (uintptr_t)(unsigned int)reinterpret_cast<uintptr_t>(l));
    __builtin_amdgcn_global_load_lds(gp, lp, 16, 0, 0);
}

// ---------------- K1: column sum-of-squares partials (no atomics) ----------
__global__ __launch_bounds__(256) void colsq_kernel(const float* __restrict__ a,
                                                    float* __restrict__ cpart) {
    int p  = blockIdx.x * 256 + threadIdx.x;
    int d0 = blockIdx.y * 64;
    float s = 0.f;
    for (int d = 0; d < 64; ++d) {
        float v = a[(size_t)(d0 + d) * P_DIM + p];
        s = fmaf(v, v, s);
    }
    cpart[(size_t)blockIdx.y * P_DIM + p] = s;
}

// ---------------- K2: z (fp32) -> zh (bf16), elementwise -------------------
__global__ __launch_bounds__(256) void zconv_kernel(const float* __restrict__ z,
                                                    unsigned short* __restrict__ zh) {
    size_t i = ((size_t)blockIdx.x * 256 + threadIdx.x) * 4;
    float4 v = *reinterpret_cast<const float4*>(z + i);
    ushort4 o;
    o.x = f2bf(v.x); o.y = f2bf(v.y); o.z = f2bf(v.z); o.w = f2bf(v.w);
    *reinterpret_cast<ushort4*>(zh + i) = o;
}

// ------- K3: a (768x1024) -> Bt (1024x768 bf16), normalized columns --------
__global__ __launch_bounds__(256) void atconv_kernel(const float* __restrict__ a,
                                                     const float* __restrict__ cpart,
                                                     unsigned short* __restrict__ Bt) {
    __shared__ float tile[64][65];
    __shared__ float linv[64];
    const int d0 = blockIdx.x * 64, p0 = blockIdx.y * 64;
    const int tid = threadIdx.x;
    if (tid < 64) {
        float s = 0.f;
        #pragma unroll
        for (int j = 0; j < D_DIM / 64; ++j)
            s += cpart[(size_t)j * P_DIM + p0 + tid];
        linv[tid] = rsqrtf(s);
    }
    #pragma unroll
    for (int pass = 0; pass < 16; ++pass) {
        int idx = pass * 256 + tid;
        int dr = idx >> 6, pc = idx & 63;
        tile[dr][pc] = a[(size_t)(d0 + dr) * P_DIM + p0 + pc];
    }
    __syncthreads();
    #pragma unroll
    for (int pass = 0; pass < 16; ++pass) {
        int idx = pass * 256 + tid;
        int pr = idx >> 6, dc = idx & 63;
        Bt[(size_t)(p0 + pr) * D_DIM + d0 + dc] = f2bf(tile[dc][pr] * linv[pr]);
    }
}

// ------- K4: fused bf16 MFMA GEMM + sincos/Chebyshev partial sums ----------
// 128x128 tile, 512 threads = 8 waves (2 wr x 4 wc), wave tile 64x32.
// Double-buffered LDS, counted vmcnt (T4), XOR-swizzled LDS via pre-swizzled
// global source (T2 + rule 21: gload_lds dest is linear, so permute source
// 16B-chunks with sc=(l&7)^((l>>3)&7); reader applies kg^(lane&7)).
__global__ __launch_bounds__(512, 4) void gemmcf_kernel(const unsigned short* __restrict__ A,
                                                        const unsigned short* __restrict__ B,
                                                        float* __restrict__ part) {
    __shared__ unsigned short AsB[2][128 * 64];
    __shared__ unsigned short BsB[2][128 * 64];
    const int tid  = threadIdx.x;
    const int lane = tid & 63;
    const int wave = tid >> 6;            // 0..7
    const int wr = wave >> 2, wc = wave & 3;

    // T1: XCD-aware swizzle (512 blocks, 8 XCDs, 64 blocks/XCD = 8 row-panels)
    const int bid = blockIdx.x + blockIdx.y * 8;
    const int swz = (bid & 7) * 64 + (bid >> 3);
    const int bx = swz & 7, by = swz >> 3;
    const int row0 = by * 128;
    const int col0 = bx * 128;

    // staging addresses: wave stages rows [wave*16, +16); source chunk swizzled
    const int srow = wave * 16 + (lane >> 3);
    const int sc   = (lane & 7) ^ ((lane >> 3) & 7);   // involution pre-swizzle
    const unsigned short* Ag = A + (size_t)(row0 + srow) * D_DIM + sc * 8;
    const unsigned short* Bg = B + (size_t)(col0 + srow) * D_DIM + sc * 8;
    const int ldsw = wave * 16 * 64;      // wave-uniform LDS base (elements)

#define STAGE(kt, db)  do { const int k0_ = (kt) * 64;                       \
        gload_lds16(Ag + k0_,             &AsB[db][ldsw]);                   \
        gload_lds16(Ag + k0_ + 8 * D_DIM, &AsB[db][ldsw + 8 * 64]);          \
        gload_lds16(Bg + k0_,             &BsB[db][ldsw]);                   \
        gload_lds16(Bg + k0_ + 8 * D_DIM, &BsB[db][ldsw + 8 * 64]); } while (0)

    f32x4 acc[4][2] = {};

    STAGE(0, 0);
    #pragma unroll
    for (int t = 0; t < KSTEPS; ++t) {
        const int cur = t & 1;
        if (t + 1 < KSTEPS) {
            STAGE(t + 1, cur ^ 1);
            asm volatile("s_waitcnt vmcnt(4)" ::: "memory");
        } else {
            asm volatile("s_waitcnt vmcnt(0)" ::: "memory");
        }
        __builtin_amdgcn_sched_barrier(0);
        __builtin_amdgcn_s_barrier();
        #pragma unroll
        for (int kk = 0; kk < 2; ++kk) {
            bf16x8 af[4], bfr[2];
            const int kg = kk * 4 + (lane >> 4);
            const int kph = (kg ^ (lane & 7)) * 8;     // swizzled read chunk
            #pragma unroll
            for (int mi = 0; mi < 4; ++mi)
                af[mi] = *reinterpret_cast<const bf16x8*>(
                    &AsB[cur][(wr * 64 + mi * 16 + (lane & 15)) * 64 + kph]);
            #pragma unroll
            for (int ni = 0; ni < 2; ++ni)
                bfr[ni] = *reinterpret_cast<const bf16x8*>(
                    &BsB[cur][(wc * 32 + ni * 16 + (lane & 15)) * 64 + kph]);
            #pragma unroll
            for (int mi = 0; mi < 4; ++mi)
                #pragma unroll
                for (int ni = 0; ni < 2; ++ni)
                    acc[mi][ni] = __builtin_amdgcn_mfma_f32_16x16x32_bf16(
                        af[mi], bfr[ni], acc[mi][ni], 0, 0, 0);
        }
        __builtin_amdgcn_s_barrier();
    }
#undef STAGE

    // ---- fused epilogue: per-column cos/sin sums over this wave's 64 rows.
    // col = wc*32 + ni*16 + (lane&15): fixed per (lane&15, ni); the 16 values
    // (mi, j) are rows of that one column; butterfly 16/32 merges quarters.
    const float dt = 0.1875f;   // 3/16 exact
    #pragma unroll
    for (int ni = 0; ni < 2; ++ni) {
        float cs[NK], ss[NK];
        #pragma unroll
        for (int k = 0; k < NK; ++k) { cs[k] = 0.f; ss[k] = 0.f; }
        #pragma unroll
        for (int mi = 0; mi < 4; ++mi)
            #pragma unroll
            for (int j = 0; j < 4; ++j) {
                float th = acc[mi][ni][j] * dt;
                float s1 = __sinf(th);
                float c1 = __cosf(th);
                float c2 = 2.f * c1;
                float ckm2 = 1.f, skm2 = 0.f;
                float ckm1 = c1,  skm1 = s1;
                cs[0] += c1; ss[0] += s1;            // k = 1
                #pragma unroll
                for (int k = 2; k <= NK; ++k) {
                    float ck = fmaf(c2, ckm1, -ckm2);
                    float sk = fmaf(c2, skm1, -skm2);
                    cs[k - 1] += ck; ss[k - 1] += sk;
                    ckm2 = ckm1; skm2 = skm1;
                    ckm1 = ck;   skm1 = sk;
                }
            }
        #pragma unroll
        for (int k = 0; k < NK; ++k) {
            cs[k] += __shfl_xor(cs[k], 16);
            cs[k] += __shfl_xor(cs[k], 32);
            ss[k] += __shfl_xor(ss[k], 16);
            ss[k] += __shfl_xor(ss[k], 32);
        }
        if (lane < 16) {
            int col = col0 + wc * 32 + ni * 16 + lane;
            size_t base = ((size_t)(by * 2 + wr) * 2 * NK) * P_DIM + col;
            #pragma unroll
            for (int k = 0; k < NK; ++k) {
                part[base + (size_t)k * P_DIM]        = cs[k];
                part[base + (size_t)(NK + k) * P_DIM] = ss[k];
            }
        }
    }
}

// ---------------- K5: parallel chunk reduction (32*1024 outputs) -----------
__global__ __launch_bounds__(256) void red1_kernel(const float* __restrict__ part,
                                                   float* __restrict__ sums) {
    int g = blockIdx.x * 256 + threadIdx.x;   // [0, 2*NK*1024)
    float s = 0.f;
    for (int c = 0; c < NCH; ++c)
        s += part[(size_t)c * 2 * NK * P_DIM + g];
    sums[g] = s;
}

// ---------------- K6: epilogue + scalar out --------------------------------
__global__ __launch_bounds__(1024) void red2_kernel(const float* __restrict__ sums,
                                                    float* __restrict__ out) {
    const int p = threadIdx.x;
    const float dt = 0.1875f;
    const float inv_n = 1.0f / (float)N_ROWS;
    float contrib = 0.f;
    #pragma unroll
    for (int k = 1; k <= NK; ++k) {
        float cm   = sums[(k - 1) * P_DIM + p] * inv_n;
        float sm   = sums[(NK + k - 1) * P_DIM + p] * inv_n;
        float tk   = dt * (float)k;
        float phik = expf(-0.5f * tk * tk);
        float wk   = (k == KNOTS - 1) ? dt : 2.f * dt;
        float d    = cm - phik;
        contrib += wk * phik * (d * d + sm * sm);
    }
    __shared__ float red[1024];
    red[p] = contrib;
    __syncthreads();
    for (int sft = 512; sft > 0; sft >>= 1) {
        if (p < sft) red[p] += red[p + sft];
        __syncthreads();
    }
    if (p == 0) out[0] = red[0] * (float)N_ROWS / (float)P_DIM;
}

extern "C" void kernel_launch(void* const* d_in, const int* in_sizes, int n_in,
                              void* d_out, int out_size, void* d_ws, size_t ws_size,
                              hipStream_t stream) {
    const float* z = (const float*)d_in[0];   // 8192 x 768
    const float* a = (const float*)d_in[1];   // 768 x 1024
    float* out = (float*)d_out;

    char* ws = (char*)d_ws;                                       // all disjoint, ~31 MB
    float*          cpart = (float*)ws;                           // 12*1024*4 = 48 KB
    unsigned short* zh    = (unsigned short*)(ws + 65536);        // 12.6 MB
    unsigned short* Bt    = (unsigned short*)(ws + 65536 + 12582912);            // 1.5 MB
    float*          part  = (float*)(ws + 65536 + 12582912 + 1572864);           // 16.8 MB
    float*          sums  = (float*)(ws + 65536 + 12582912 + 1572864 + 16777216);// 128 KB

    colsq_kernel<<<dim3(P_DIM / 256, D_DIM / 64), 256, 0, stream>>>(a, cpart);
    zconv_kernel<<<dim3(N_ROWS * D_DIM / (256 * 4)), 256, 0, stream>>>(z, zh);
    atconv_kernel<<<dim3(D_DIM / 64, P_DIM / 64), 256, 0, stream>>>(a, cpart, Bt);
    gemmcf_kernel<<<dim3(P_DIM / 128, N_ROWS / 128), 512, 0, stream>>>(zh, Bt, part);
    red1_kernel<<<dim3(2 * NK * P_DIM / 256), 256, 0, stream>>>(part, sums);
    red2_kernel<<<1, 1024, 0, stream>>>(sums, out);
}

// Round 9
// 119.495 us; speedup vs baseline: 3.6615x; 1.0113x over previous
//
#include <hip/hip_runtime.h>
#include <math.h>

typedef __attribute__((ext_vector_type(8))) short bf16x8;
typedef __attribute__((ext_vector_type(4))) float f32x4;

#define N_ROWS 8192
#define D_DIM  768
#define P_DIM  1024
#define KNOTS  17
#define NK     16                 // knots 1..16 (k=0 term is exactly zero)
#define NCH    128                // partial chunks: 64 row-blocks x 2 wr-halves
#define KSTEPS 12                 // 768 / 64
#define ALD    72                 // padded LDS row stride for A (bf16 elems)

// ---- bf16 round-to-nearest-even (bit trick; proven since round 1) ----
__device__ inline unsigned short f2bf(float f) {
    union { float f; unsigned int u; } x; x.f = f;
    unsigned int r = x.u + 0x7FFFu + ((x.u >> 16) & 1u);
    return (unsigned short)(r >> 16);
}

// ---- 8x f32 -> bf16x8 via bit trick (no asm) ----
__device__ inline bf16x8 pack8(float4 a, float4 b) {
    union { unsigned short s[8]; bf16x8 v; } r;
    r.s[0] = f2bf(a.x); r.s[1] = f2bf(a.y); r.s[2] = f2bf(a.z); r.s[3] = f2bf(a.w);
    r.s[4] = f2bf(b.x); r.s[5] = f2bf(b.y); r.s[6] = f2bf(b.z); r.s[7] = f2bf(b.w);
    return r.v;
}

// ---- async global->LDS, 16B per lane (LDS base wave-uniform, HW adds lane*16)
__device__ inline void gload_lds16(const unsigned short* g, const unsigned short* l) {
    auto gp = reinterpret_cast<const __attribute__((address_space(1))) char*>(
        reinterpret_cast<uintptr_t>(g));
    auto lp = reinterpret_cast<__attribute__((address_space(3))) char*>(
        (uintptr_t)(unsigned int)reinterpret_cast<uintptr_t>(l));
    __builtin_amdgcn_global_load_lds(gp, lp, 16, 0, 0);
}

// ---------------- K1: column sum-of-squares partials (no atomics) ----------
__global__ __launch_bounds__(256) void colsq_kernel(const float* __restrict__ a,
                                                    float* __restrict__ cpart) {
    int p  = blockIdx.x * 256 + threadIdx.x;
    int d0 = blockIdx.y * 64;
    float s = 0.f;
    for (int d = 0; d < 64; ++d) {
        float v = a[(size_t)(d0 + d) * P_DIM + p];
        s = fmaf(v, v, s);
    }
    cpart[(size_t)blockIdx.y * P_DIM + p] = s;
}

// ------- K2: a (768x1024) -> Bt (1024x768 bf16), normalized columns --------
__global__ __launch_bounds__(256) void atconv_kernel(const float* __restrict__ a,
                                                     const float* __restrict__ cpart,
                                                     unsigned short* __restrict__ Bt) {
    __shared__ float tile[64][65];
    __shared__ float linv[64];
    const int d0 = blockIdx.x * 64, p0 = blockIdx.y * 64;
    const int tid = threadIdx.x;
    if (tid < 64) {
        float s = 0.f;
        #pragma unroll
        for (int j = 0; j < D_DIM / 64; ++j)
            s += cpart[(size_t)j * P_DIM + p0 + tid];
        linv[tid] = rsqrtf(s);
    }
    #pragma unroll
    for (int pass = 0; pass < 16; ++pass) {
        int idx = pass * 256 + tid;
        int dr = idx >> 6, pc = idx & 63;
        tile[dr][pc] = a[(size_t)(d0 + dr) * P_DIM + p0 + pc];
    }
    __syncthreads();
    #pragma unroll
    for (int pass = 0; pass < 16; ++pass) {
        int idx = pass * 256 + tid;
        int pr = idx >> 6, dc = idx & 63;
        Bt[(size_t)(p0 + pr) * D_DIM + d0 + dc] = f2bf(tile[dc][pr] * linv[pr]);
    }
}

// ------- K3: fused GEMM (fp32 A converted in-flight) + cos/sin partials ----
// 128x128 tile, 512 thr = 8 waves (2wr x 4wc), BK=64, dbuf LDS.
// A: reg-staged (global fp32 -> f2bf -> ds_write_b128), padded stride 72
//    => linear reads, 2-way banks (free). Loads issued 1 step early.
// B: gload_lds direct with XOR-pre-swizzled source (round-7 scheme, proven).
// Schedule: 1 barrier/step with FULL drains (conservative; no counted vmcnt).
__global__ __launch_bounds__(512, 4) void gemmcf_kernel(const float* __restrict__ Z,
                                                        const unsigned short* __restrict__ B,
                                                        float* __restrict__ part) {
    __shared__ unsigned short AsB[2][128 * ALD];
    __shared__ unsigned short BsB[2][128 * 64];
    const int tid  = threadIdx.x;
    const int lane = tid & 63;
    const int wave = tid >> 6;            // 0..7
    const int wr = wave >> 2, wc = wave & 3;

    // T1: XCD-aware swizzle (512 blocks, 8 XCDs, 64 blocks/XCD = 8 row-panels)
    const int bid = blockIdx.x + blockIdx.y * 8;
    const int swz = (bid & 7) * 64 + (bid >> 3);
    const int bx = swz & 7, by = swz >> 3;
    const int row0 = by * 128;
    const int col0 = bx * 128;

    // A reg-staging geometry: lane covers tile-row aR, chunks {ac, ac+4} of 8
    const int aR = wave * 16 + (lane >> 2);
    const int ac = lane & 3;
    const float* Zg = Z + (size_t)(row0 + aR) * D_DIM + ac * 8;

    // B staging: wave stages rows [wave*16,+16), source chunk pre-swizzled
    const int srow = wave * 16 + (lane >> 3);
    const int sc   = (lane & 7) ^ ((lane >> 3) & 7);
    const unsigned short* Bg = B + (size_t)(col0 + srow) * D_DIM + sc * 8;
    const int ldsw = wave * 16 * 64;

    float4 ar0, ar1, ar2, ar3;            // A(t+1) in flight (16 fp32)

#define ALOAD(kt) do { const float* zp_ = Zg + (kt) * 64;                    \
        ar0 = *reinterpret_cast<const float4*>(zp_);                         \
        ar1 = *reinterpret_cast<const float4*>(zp_ + 4);                     \
        ar2 = *reinterpret_cast<const float4*>(zp_ + 32);                    \
        ar3 = *reinterpret_cast<const float4*>(zp_ + 36); } while (0)
#define AWRITE(db) do {                                                      \
        *reinterpret_cast<bf16x8*>(&AsB[db][aR * ALD + ac * 8])       = pack8(ar0, ar1); \
        *reinterpret_cast<bf16x8*>(&AsB[db][aR * ALD + (ac + 4) * 8]) = pack8(ar2, ar3); } while (0)
#define BSTAGE(kt, db) do { const int k0_ = (kt) * 64;                       \
        gload_lds16(Bg + k0_,             &BsB[db][ldsw]);                   \
        gload_lds16(Bg + k0_ + 8 * D_DIM, &BsB[db][ldsw + 8 * 64]); } while (0)
#define DRAIN_BARRIER() do {                                                 \
        asm volatile("s_waitcnt vmcnt(0) lgkmcnt(0)" ::: "memory");          \
        __builtin_amdgcn_sched_barrier(0);                                   \
        __builtin_amdgcn_s_barrier(); } while (0)

    f32x4 acc[4][2] = {};

    // prologue: tile 0 into buf0; A(1) in regs; full drain + barrier
    ALOAD(0);
    AWRITE(0);                 // compiler auto-waits ar deps
    BSTAGE(0, 0);
    ALOAD(1);
    DRAIN_BARRIER();

    #pragma unroll
    for (int t = 0; t < KSTEPS; ++t) {
        const int cur = t & 1;
        if (t + 1 < KSTEPS) {
            AWRITE(cur ^ 1);                     // A(t+1) regs -> LDS
            BSTAGE(t + 1, cur ^ 1);
            if (t + 2 < KSTEPS) ALOAD(t + 2);    // overlaps compute below
        }
        #pragma unroll
        for (int kk = 0; kk < 2; ++kk) {
            bf16x8 af[4], bfr[2];
            const int kg = kk * 4 + (lane >> 4);
            const int kbp = (kg ^ (lane & 7)) * 8;     // B swizzled read chunk
            #pragma unroll
            for (int mi = 0; mi < 4; ++mi)
                af[mi] = *reinterpret_cast<const bf16x8*>(
                    &AsB[cur][(wr * 64 + mi * 16 + (lane & 15)) * ALD + kg * 8]);
            #pragma unroll
            for (int ni = 0; ni < 2; ++ni)
                bfr[ni] = *reinterpret_cast<const bf16x8*>(
                    &BsB[cur][(wc * 32 + ni * 16 + (lane & 15)) * 64 + kbp]);
            #pragma unroll
            for (int mi = 0; mi < 4; ++mi)
                #pragma unroll
                for (int ni = 0; ni < 2; ++ni)
                    acc[mi][ni] = __builtin_amdgcn_mfma_f32_16x16x32_bf16(
                        af[mi], bfr[ni], acc[mi][ni], 0, 0, 0);
        }
        if (t + 1 < KSTEPS) DRAIN_BARRIER();
    }
#undef ALOAD
#undef AWRITE
#undef BSTAGE
#undef DRAIN_BARRIER

    // ---- fused epilogue: per-column cos/sin sums over this wave's 64 rows.
    const float dt = 0.1875f;   // 3/16 exact
    #pragma unroll
    for (int ni = 0; ni < 2; ++ni) {
        float cs[NK], ss[NK];
        #pragma unroll
        for (int k = 0; k < NK; ++k) { cs[k] = 0.f; ss[k] = 0.f; }
        #pragma unroll
        for (int mi = 0; mi < 4; ++mi)
            #pragma unroll
            for (int j = 0; j < 4; ++j) {
                float th = acc[mi][ni][j] * dt;
                float s1 = __sinf(th);
                float c1 = __cosf(th);
                float c2 = 2.f * c1;
                float ckm2 = 1.f, skm2 = 0.f;
                float ckm1 = c1,  skm1 = s1;
                cs[0] += c1; ss[0] += s1;            // k = 1
                #pragma unroll
                for (int k = 2; k <= NK; ++k) {
                    float ck = fmaf(c2, ckm1, -ckm2);
                    float sk = fmaf(c2, skm1, -skm2);
                    cs[k - 1] += ck; ss[k - 1] += sk;
                    ckm2 = ckm1; skm2 = skm1;
                    ckm1 = ck;   skm1 = sk;
                }
            }
        #pragma unroll
        for (int k = 0; k < NK; ++k) {
            cs[k] += __shfl_xor(cs[k], 16);
            cs[k] += __shfl_xor(cs[k], 32);
            ss[k] += __shfl_xor(ss[k], 16);
            ss[k] += __shfl_xor(ss[k], 32);
        }
        if (lane < 16) {
            int col = col0 + wc * 32 + ni * 16 + lane;
            size_t base = ((size_t)(by * 2 + wr) * 2 * NK) * P_DIM + col;
            #pragma unroll
            for (int k = 0; k < NK; ++k) {
                part[base + (size_t)k * P_DIM]        = cs[k];
                part[base + (size_t)(NK + k) * P_DIM] = ss[k];
            }
        }
    }
}

// ---------------- K4: parallel chunk reduction (32*1024 outputs) -----------
__global__ __launch_bounds__(256) void red1_kernel(const float* __restrict__ part,
                                                   float* __restrict__ sums) {
    int g = blockIdx.x * 256 + threadIdx.x;   // [0, 2*NK*1024)
    float s = 0.f;
    for (int c = 0; c < NCH; ++c)
        s += part[(size_t)c * 2 * NK * P_DIM + g];
    sums[g] = s;
}

// ---------------- K5: epilogue + scalar out --------------------------------
__global__ __launch_bounds__(1024) void red2_kernel(const float* __restrict__ sums,
                                                    float* __restrict__ out) {
    const int p = threadIdx.x;
    const float dt = 0.1875f;
    const float inv_n = 1.0f / (float)N_ROWS;
    float contrib = 0.f;
    #pragma unroll
    for (int k = 1; k <= NK; ++k) {
        float cm   = sums[(k - 1) * P_DIM + p] * inv_n;
        float sm   = sums[(NK + k - 1) * P_DIM + p] * inv_n;
        float tk   = dt * (float)k;
        float phik = expf(-0.5f * tk * tk);
        float wk   = (k == KNOTS - 1) ? dt : 2.f * dt;
        float d    = cm - phik;
        contrib += wk * phik * (d * d + sm * sm);
    }
    __shared__ float red[1024];
    red[p] = contrib;
    __syncthreads();
    for (int sft = 512; sft > 0; sft >>= 1) {
        if (p < sft) red[p] += red[p + sft];
        __syncthreads();
    }
    if (p == 0) out[0] = red[0] * (float)N_ROWS / (float)P_DIM;
}

extern "C" void kernel_launch(void* const* d_in, const int* in_sizes, int n_in,
                              void* d_out, int out_size, void* d_ws, size_t ws_size,
                              hipStream_t stream) {
    const float* z = (const float*)d_in[0];   // 8192 x 768
    const float* a = (const float*)d_in[1];   // 768 x 1024
    float* out = (float*)d_out;

    char* ws = (char*)d_ws;                                       // ~18.5 MB used
    float*          cpart = (float*)ws;                           // 48 KB (pad 64K)
    unsigned short* Bt    = (unsigned short*)(ws + 65536);        // 1.5 MB
    float*          part  = (float*)(ws + 65536 + 1572864);       // 16.8 MB
    float*          sums  = (float*)(ws + 65536 + 1572864 + 16777216); // 128 KB

    colsq_kernel<<<dim3(P_DIM / 256, D_DIM / 64), 256, 0, stream>>>(a, cpart);
    atconv_kernel<<<dim3(D_DIM / 64, P_DIM / 64), 256, 0, stream>>>(a, cpart, Bt);
    gemmcf_kernel<<<dim3(P_DIM / 128, N_ROWS / 128), 512, 0, stream>>>(z, Bt, part);
    red1_kernel<<<dim3(2 * NK * P_DIM / 256), 256, 0, stream>>>(part, sums);
    red2_kernel<<<1, 1024, 0, stream>>>(sums, out);
}